// Round 1
// baseline (276.735 us; speedup 1.0000x reference)
//
#include <hip/hip_runtime.h>

// Batched CBF-QP via dual FISTA. One thread per batch element.
// Row layout (25 active rows; the all-zero "extra" row is provably inert and dropped):
//   3 slack rows, 10 obstacle rows, 7 neighbor rows, 1 connectivity row, 4 box rows.

namespace {
constexpr int NOBS = 10;
constexpr int NNEI = 7;
constexpr int N_POWER = 30;
constexpr int N_FISTA = 300;
constexpr float PINV_U = 0.5f;          // 1/2 for u components
constexpr float PINV_S = 1.0f / 200.0f; // 1/(2*W_SLACK)
constexpr float BIG = 1000.0f;
}

__global__ __launch_bounds__(64) void cbf_fista_kernel(
    const float* __restrict__ u_nom,    // (B,2)
    const float* __restrict__ v_cur,    // (B,1)
    const float* __restrict__ p_obs,    // (B,10,2)
    const float* __restrict__ obs_mask, // (B,10)
    const float* __restrict__ p_ag,     // (B,7,2)
    const float* __restrict__ v_ag,     // (B,7,2)
    const float* __restrict__ ag_mask,  // (B,7)
    const float* __restrict__ p_c,      // (B,1,2)
    const float* __restrict__ v_c,      // (B,1,2)
    const float* __restrict__ c_mask,   // (B,1)
    float* __restrict__ out,            // (B,2)
    int B)
{
    const int b = blockIdx.x * 64 + threadIdx.x;
    if (b >= B) return;

    const float v  = v_cur[b];
    const float q0 = -2.0f * u_nom[2 * b];
    const float q1 = -2.0f * u_nom[2 * b + 1];

    // ---- Build sparse row coefficients (registers) ----
    float og0[NOBS], og1[NOBS], ogm[NOBS], ob[NOBS];
#pragma unroll
    for (int i = 0; i < NOBS; ++i) {
        const float lx = p_obs[(b * NOBS + i) * 2];
        const float ly = p_obs[(b * NOBS + i) * 2 + 1];
        const float m  = obs_mask[b * NOBS + i];
        const float h   = lx * lx + ly * ly - 0.25f;       // D_OBS^2
        const float hd  = -2.0f * lx * v;
        const float rhs = 2.0f * v * v + 3.0f * hd + 2.0f * h; // DAMP=3, STIFF=2
        og0[i] = 2.0f * lx * m;
        og1[i] = 2.0f * ly * v * m;
        ogm[i] = -m;
        ob[i]  = (m > 0.0f) ? rhs : BIG;
    }
    float ng0[NNEI], ng1[NNEI], ngm[NNEI], nb[NNEI];
#pragma unroll
    for (int j = 0; j < NNEI; ++j) {
        const float ax  = p_ag[(b * NNEI + j) * 2];
        const float ay  = p_ag[(b * NNEI + j) * 2 + 1];
        const float vjx = v_ag[(b * NNEI + j) * 2];
        const float vjy = v_ag[(b * NNEI + j) * 2 + 1];
        const float m   = ag_mask[b * NNEI + j];
        const float h   = ax * ax + ay * ay - 0.64f;       // D_SAFE^2
        const float hd  = -2.0f * ax * v + 2.0f * (ax * vjx + ay * vjy);
        const float hdd = 2.0f * v * v - 2.0f * v * vjx
                        + 2.0f * (-v * vjx + vjx * vjx + vjy * vjy);
        const float rhs = hdd + 3.0f * hd + 2.0f * h;      // DAMP_A=3, STIFF_A=2
        ng0[j] = 2.0f * ax * m;
        ng1[j] = (2.0f * ay * v - 2.0f * ay * vjx + 2.0f * ax * vjy) * m;
        ngm[j] = -m;
        nb[j]  = (m > 0.0f) ? rhs : BIG;
    }
    float cg0, cg1, cgm, cb;
    {
        const float cx  = p_c[2 * b];
        const float cy  = p_c[2 * b + 1];
        const float cvx = v_c[2 * b];
        const float cvy = v_c[2 * b + 1];
        const float m   = c_mask[b];
        const float h   = 25.0f - (cx * cx + cy * cy);     // D_MAX^2
        const float hd  = 2.0f * cx * v - 2.0f * (cx * cvx + cy * cvy);
        const float hdd = -(2.0f * v * v - 2.0f * v * cvx
                          + 2.0f * (-v * cvx + cvx * cvx + cvy * cvy));
        const float rhs = hdd + 3.0f * hd + 2.0f * h;      // DAMP_CN=3, STIFF_CN=2
        cg0 = -2.0f * cx * m;
        cg1 = -(2.0f * cy * v - 2.0f * cy * cvx + 2.0f * cx * cvy) * m;
        cgm = -m;
        cb  = (m > 0.0f) ? rhs : BIG;
    }

    // ---- Power iteration for L = lambda_max(A Pinv A^T), Mm never materialized ----
    float pvS0 = 1.0f, pvS1 = 1.0f, pvS2 = 1.0f;
    float pvO[NOBS], pvN[NNEI];
#pragma unroll
    for (int i = 0; i < NOBS; ++i) pvO[i] = 1.0f;
#pragma unroll
    for (int j = 0; j < NNEI; ++j) pvN[j] = 1.0f;
    float pvC = 1.0f, pvB0 = 1.0f, pvB1 = 1.0f, pvB2 = 1.0f, pvB3 = 1.0f;

#pragma unroll 1
    for (int it = 0; it < N_POWER; ++it) {
        float t0 = pvB1 - pvB0;
        float t1 = pvB3 - pvB2;
        float t2 = -pvS0, t3 = -pvS1, t4 = -pvS2;
#pragma unroll
        for (int i = 0; i < NOBS; ++i) {
            t0 += og0[i] * pvO[i];
            t1 += og1[i] * pvO[i];
            t2 += ogm[i] * pvO[i];
        }
#pragma unroll
        for (int j = 0; j < NNEI; ++j) {
            t0 += ng0[j] * pvN[j];
            t1 += ng1[j] * pvN[j];
            t3 += ngm[j] * pvN[j];
        }
        t0 += cg0 * pvC; t1 += cg1 * pvC; t4 += cgm * pvC;

        const float x0 = PINV_U * t0, x1 = PINV_U * t1;
        const float x2 = PINV_S * t2, x3 = PINV_S * t3, x4 = PINV_S * t4;

        const float wS0 = -x2, wS1 = -x3, wS2 = -x4;
        float wO[NOBS], wN[NNEI];
        float nsq = wS0 * wS0 + wS1 * wS1 + wS2 * wS2;
#pragma unroll
        for (int i = 0; i < NOBS; ++i) {
            wO[i] = og0[i] * x0 + og1[i] * x1 + ogm[i] * x2;
            nsq += wO[i] * wO[i];
        }
#pragma unroll
        for (int j = 0; j < NNEI; ++j) {
            wN[j] = ng0[j] * x0 + ng1[j] * x1 + ngm[j] * x3;
            nsq += wN[j] * wN[j];
        }
        const float wC = cg0 * x0 + cg1 * x1 + cgm * x4;
        const float wB0 = -x0, wB1 = x0, wB2 = -x1, wB3 = x1;
        nsq += wC * wC + wB0 * wB0 + wB1 * wB1 + wB2 * wB2 + wB3 * wB3;

        const float inv = 1.0f / (sqrtf(nsq) + 1e-12f);
        pvS0 = wS0 * inv; pvS1 = wS1 * inv; pvS2 = wS2 * inv;
#pragma unroll
        for (int i = 0; i < NOBS; ++i) pvO[i] = wO[i] * inv;
#pragma unroll
        for (int j = 0; j < NNEI; ++j) pvN[j] = wN[j] * inv;
        pvC = wC * inv;
        pvB0 = wB0 * inv; pvB1 = wB1 * inv; pvB2 = wB2 * inv; pvB3 = wB3 * inv;
    }
    float step;
    {
        float t0 = pvB1 - pvB0;
        float t1 = pvB3 - pvB2;
        float t2 = -pvS0, t3 = -pvS1, t4 = -pvS2;
#pragma unroll
        for (int i = 0; i < NOBS; ++i) {
            t0 += og0[i] * pvO[i];
            t1 += og1[i] * pvO[i];
            t2 += ogm[i] * pvO[i];
        }
#pragma unroll
        for (int j = 0; j < NNEI; ++j) {
            t0 += ng0[j] * pvN[j];
            t1 += ng1[j] * pvN[j];
            t3 += ngm[j] * pvN[j];
        }
        t0 += cg0 * pvC; t1 += cg1 * pvC; t4 += cgm * pvC;
        // L = v^T Mm v = (A^T v)^T Pinv (A^T v) since v is unit-normalized
        const float L = PINV_U * (t0 * t0 + t1 * t1)
                      + PINV_S * (t2 * t2 + t3 * t3 + t4 * t4);
        step = 1.0f / (L + 1e-6f);
    }

    // ---- FISTA on the dual ----
    float laS0 = 0.f, laS1 = 0.f, laS2 = 0.f;
    float laO[NOBS], laN[NNEI];
    float yO[NOBS], yN[NNEI];
#pragma unroll
    for (int i = 0; i < NOBS; ++i) { laO[i] = 0.f; yO[i] = 0.f; }
#pragma unroll
    for (int j = 0; j < NNEI; ++j) { laN[j] = 0.f; yN[j] = 0.f; }
    float laC = 0.f, laB0 = 0.f, laB1 = 0.f, laB2 = 0.f, laB3 = 0.f;
    float yS0 = 0.f, yS1 = 0.f, yS2 = 0.f;
    float yC = 0.f, yB0 = 0.f, yB1 = 0.f, yB2 = 0.f, yB3 = 0.f;
    float tk = 1.0f;

#pragma unroll 1
    for (int it = 0; it < N_FISTA; ++it) {
        // x(y) = -(q + A^T y) * Pinv
        float s0 = q0 + (yB1 - yB0);
        float s1 = q1 + (yB3 - yB2);
        float s2 = -yS0, s3 = -yS1, s4 = -yS2;
#pragma unroll
        for (int i = 0; i < NOBS; ++i) {
            s0 += og0[i] * yO[i];
            s1 += og1[i] * yO[i];
            s2 += ogm[i] * yO[i];
        }
#pragma unroll
        for (int j = 0; j < NNEI; ++j) {
            s0 += ng0[j] * yN[j];
            s1 += ng1[j] * yN[j];
            s3 += ngm[j] * yN[j];
        }
        s0 += cg0 * yC; s1 += cg1 * yC; s4 += cgm * yC;
        const float x0 = -s0 * PINV_U, x1 = -s1 * PINV_U;
        const float x2 = -s2 * PINV_S, x3 = -s3 * PINV_S, x4 = -s4 * PINV_S;

        const float tk1  = 0.5f * (1.0f + sqrtf(1.0f + 4.0f * tk * tk));
        const float beta = (tk - 1.0f) / tk1;
        tk = tk1;

        auto upd = [&](float& la, float& yy, float resid) {
            const float ln = fmaxf(yy + step * resid, 0.0f);
            const float yn = ln + beta * (ln - la);
            la = ln;
            yy = yn;
        };

        upd(laS0, yS0, -x2);
        upd(laS1, yS1, -x3);
        upd(laS2, yS2, -x4);
#pragma unroll
        for (int i = 0; i < NOBS; ++i)
            upd(laO[i], yO[i], og0[i] * x0 + og1[i] * x1 + ogm[i] * x2 - ob[i]);
#pragma unroll
        for (int j = 0; j < NNEI; ++j)
            upd(laN[j], yN[j], ng0[j] * x0 + ng1[j] * x1 + ngm[j] * x3 - nb[j]);
        upd(laC, yC, cg0 * x0 + cg1 * x1 + cgm * x4 - cb);
        upd(laB0, yB0, -x0 - 2.0f);  // A_MAX
        upd(laB1, yB1,  x0 - 2.0f);
        upd(laB2, yB2, -x1 - 1.0f);  // W_MAX
        upd(laB3, yB3,  x1 - 1.0f);
    }

    // ---- Final primal from lam ----
    float s0 = q0 + (laB1 - laB0);
    float s1 = q1 + (laB3 - laB2);
#pragma unroll
    for (int i = 0; i < NOBS; ++i) {
        s0 += og0[i] * laO[i];
        s1 += og1[i] * laO[i];
    }
#pragma unroll
    for (int j = 0; j < NNEI; ++j) {
        s0 += ng0[j] * laN[j];
        s1 += ng1[j] * laN[j];
    }
    s0 += cg0 * laC;
    s1 += cg1 * laC;
    out[2 * b]     = -s0 * PINV_U;
    out[2 * b + 1] = -s1 * PINV_U;
}

extern "C" void kernel_launch(void* const* d_in, const int* in_sizes, int n_in,
                              void* d_out, int out_size, void* d_ws, size_t ws_size,
                              hipStream_t stream) {
    const float* u_nom    = (const float*)d_in[0];
    const float* v_cur    = (const float*)d_in[1];
    const float* p_obs    = (const float*)d_in[2];
    const float* obs_mask = (const float*)d_in[3];
    const float* p_ag     = (const float*)d_in[4];
    const float* v_ag     = (const float*)d_in[5];
    const float* ag_mask  = (const float*)d_in[6];
    const float* p_c      = (const float*)d_in[7];
    const float* v_c      = (const float*)d_in[8];
    const float* c_mask   = (const float*)d_in[9];
    float* out = (float*)d_out;

    const int B = in_sizes[0] / 2;
    const int grid = (B + 63) / 64;
    cbf_fista_kernel<<<grid, 64, 0, stream>>>(
        u_nom, v_cur, p_obs, obs_mask, p_ag, v_ag, ag_mask, p_c, v_c, c_mask, out, B);
}

// Round 2
// 193.908 us; speedup vs baseline: 1.4271x; 1.4271x over previous
//
#include <hip/hip_runtime.h>

// Batched CBF-QP dual FISTA, 4 lanes per problem (column-local row split).
//
// 25 active constraint rows (the all-zero "extra" row is provably inert):
//   sub=0: obs rows 0..6                        (slack col 2 via rA)
//   sub=1: obs 7..9, slack0(col2), box_a-, box_a+, pad
//   sub=2: nei 0..5, slack1(col3)               (slack col 3 via rA)
//   sub=3: nei6(col3 via rA), conn(col4 via rB), slack2(col4), box_w-, box_w+, 2 pads
// s0,s1 reduced over the full quad (xor1+xor2 DPP); sA reduced over the xor1
// pair only (lanes {0,1} share col2, {2,3} share col3); sB over the pair gives
// col4 to lanes {2,3}. Pad rows: all-zero coeffs, b=BIG -> lambda stays 0.

namespace {
constexpr int N_POWER = 30;
constexpr int N_FISTA = 300;
constexpr float PINV_S = 1.0f / 200.0f;  // 1/(2*W_SLACK)
constexpr float BIG = 1000.0f;
constexpr int SLOTS = 7;
}

template <int CTRL>
__device__ __forceinline__ float dpp_xor_add(float x) {
    // CTRL: 0xB1 = quad_perm(1,0,3,2) = xor1 ; 0x4E = quad_perm(2,3,0,1) = xor2
    int perm = __builtin_amdgcn_mov_dpp(__float_as_int(x), CTRL, 0xF, 0xF, true);
    return x + __int_as_float(perm);
}

__global__ __launch_bounds__(256) void cbf_fista4(
    const float* __restrict__ u_nom,    // (B,2)
    const float* __restrict__ v_cur,    // (B,1)
    const float* __restrict__ p_obs,    // (B,10,2)
    const float* __restrict__ obs_mask, // (B,10)
    const float* __restrict__ p_ag,     // (B,7,2)
    const float* __restrict__ v_ag,     // (B,7,2)
    const float* __restrict__ ag_mask,  // (B,7)
    const float* __restrict__ p_c,      // (B,1,2)
    const float* __restrict__ v_c,      // (B,1,2)
    const float* __restrict__ c_mask,   // (B,1)
    float* __restrict__ out,            // (B,2)
    int B)
{
    const int t = blockIdx.x * 256 + threadIdx.x;
    const int p = t >> 2;
    const int sub = t & 3;
    if (p >= B) return;

    const float v  = v_cur[p];
    const float u0 = u_nom[2 * p];
    const float u1 = u_nom[2 * p + 1];

    float r0[SLOTS], r1[SLOTS], rA[SLOTS], rB[SLOTS], rb[SLOTS];
#pragma unroll
    for (int s = 0; s < SLOTS; ++s) { r0[s] = 0.f; r1[s] = 0.f; rA[s] = 0.f; rB[s] = 0.f; rb[s] = BIG; }

    auto obs_row = [&](int i, int s) {
        const float lx = p_obs[(p * 10 + i) * 2];
        const float ly = p_obs[(p * 10 + i) * 2 + 1];
        const float m  = obs_mask[p * 10 + i];
        const float h   = lx * lx + ly * ly - 0.25f;            // D_OBS^2
        const float hd  = -2.f * lx * v;
        const float rhs = 2.f * v * v + 3.f * hd + 2.f * h;     // DAMP=3, STIFF=2
        r0[s] = 2.f * lx * m;
        r1[s] = 2.f * ly * v * m;
        rA[s] = -m;
        rb[s] = (m > 0.f) ? rhs : BIG;
    };
    auto nei_row = [&](int j, int s) {
        const float ax  = p_ag[(p * 7 + j) * 2];
        const float ay  = p_ag[(p * 7 + j) * 2 + 1];
        const float vjx = v_ag[(p * 7 + j) * 2];
        const float vjy = v_ag[(p * 7 + j) * 2 + 1];
        const float m   = ag_mask[p * 7 + j];
        const float h   = ax * ax + ay * ay - 0.64f;            // D_SAFE^2
        const float hd  = -2.f * ax * v + 2.f * (ax * vjx + ay * vjy);
        const float hdd = 2.f * v * v - 2.f * v * vjx
                        + 2.f * (-v * vjx + vjx * vjx + vjy * vjy);
        const float rhs = hdd + 3.f * hd + 2.f * h;             // DAMP_A=3, STIFF_A=2
        r0[s] = 2.f * ax * m;
        r1[s] = (2.f * ay * v - 2.f * ay * vjx + 2.f * ax * vjy) * m;
        rA[s] = -m;
        rb[s] = (m > 0.f) ? rhs : BIG;
    };

    if (sub == 0) {
        obs_row(0, 0); obs_row(1, 1); obs_row(2, 2); obs_row(3, 3);
        obs_row(4, 4); obs_row(5, 5); obs_row(6, 6);
    } else if (sub == 1) {
        obs_row(7, 0); obs_row(8, 1); obs_row(9, 2);
        rA[3] = -1.f; rb[3] = 0.f;     // slack0: -delta_obs <= 0  (col2)
        r0[4] = -1.f; rb[4] = 2.f;     // -a <= A_MAX
        r0[5] =  1.f; rb[5] = 2.f;     //  a <= A_MAX
    } else if (sub == 2) {
        nei_row(0, 0); nei_row(1, 1); nei_row(2, 2);
        nei_row(3, 3); nei_row(4, 4); nei_row(5, 5);
        rA[6] = -1.f; rb[6] = 0.f;     // slack1: -delta_agent <= 0 (col3)
    } else {
        nei_row(6, 0);                  // col3 via rA (pair-reduced with sub=2)
        {
            const float cx  = p_c[2 * p];
            const float cy  = p_c[2 * p + 1];
            const float cvx = v_c[2 * p];
            const float cvy = v_c[2 * p + 1];
            const float m   = c_mask[p];
            const float h   = 25.f - (cx * cx + cy * cy);       // D_MAX^2
            const float hd  = 2.f * cx * v - 2.f * (cx * cvx + cy * cvy);
            const float hdd = -(2.f * v * v - 2.f * v * cvx
                              + 2.f * (-v * cvx + cvx * cvx + cvy * cvy));
            const float rhs = hdd + 3.f * hd + 2.f * h;         // DAMP_CN=3, STIFF_CN=2
            r0[1] = -2.f * cx * m;
            r1[1] = -(2.f * cy * v - 2.f * cy * cvx + 2.f * cx * cvy) * m;
            rB[1] = -m;
            rb[1] = (m > 0.f) ? rhs : BIG;
        }
        rB[2] = -1.f; rb[2] = 0.f;     // slack2: -delta_conn <= 0 (col4)
        r1[3] = -1.f; rb[3] = 1.f;     // -w <= W_MAX
        r1[4] =  1.f; rb[4] = 1.f;     //  w <= W_MAX
    }

    // weights so each slack column is counted exactly once in L = v^T M v
    const float wA = (sub == 0 || sub == 2) ? 1.f : 0.f;  // col2 (lane0), col3 (lane2)
    const float wB = (sub == 3) ? 1.f : 0.f;              // col4 (lane3)

    // ---- Power iteration: L = lambda_max(A Pinv A^T) ----
    float pv[SLOTS];
#pragma unroll
    for (int s = 0; s < SLOTS; ++s) pv[s] = 1.f;

    float step = 0.f;
#pragma unroll 1
    for (int it = 0; it <= N_POWER; ++it) {
        float s0 = 0.f, s1 = 0.f, sA = 0.f, sB = 0.f;
#pragma unroll
        for (int s = 0; s < SLOTS; ++s) {
            s0 = fmaf(r0[s], pv[s], s0);
            s1 = fmaf(r1[s], pv[s], s1);
            sA = fmaf(rA[s], pv[s], sA);
            sB = fmaf(rB[s], pv[s], sB);
        }
        s0 = dpp_xor_add<0xB1>(s0); s0 = dpp_xor_add<0x4E>(s0);
        s1 = dpp_xor_add<0xB1>(s1); s1 = dpp_xor_add<0x4E>(s1);
        sA = dpp_xor_add<0xB1>(sA);
        sB = dpp_xor_add<0xB1>(sB);
        if (it == N_POWER) {
            float c = wA * sA * sA + wB * sB * sB;
            c = dpp_xor_add<0xB1>(c); c = dpp_xor_add<0x4E>(c);
            const float L = 0.5f * (s0 * s0 + s1 * s1) + PINV_S * c;
            step = __builtin_amdgcn_rcpf(L + 1e-6f);
            break;
        }
        const float x0 = 0.5f * s0, x1 = 0.5f * s1;
        const float xA = PINV_S * sA, xB = PINV_S * sB;
        float w[SLOTS], nsq = 0.f;
#pragma unroll
        for (int s = 0; s < SLOTS; ++s) {
            w[s] = fmaf(r0[s], x0, fmaf(r1[s], x1, fmaf(rA[s], xA, rB[s] * xB)));
            nsq = fmaf(w[s], w[s], nsq);
        }
        nsq = dpp_xor_add<0xB1>(nsq); nsq = dpp_xor_add<0x4E>(nsq);
        const float inv = __builtin_amdgcn_rcpf(__builtin_amdgcn_sqrtf(nsq) + 1e-12f);
#pragma unroll
        for (int s = 0; s < SLOTS; ++s) pv[s] = w[s] * inv;
    }

    // ---- FISTA on the dual ----
    float la[SLOTS], yv[SLOTS];
#pragma unroll
    for (int s = 0; s < SLOTS; ++s) { la[s] = 0.f; yv[s] = 0.f; }
    float tk = 1.f;

#pragma unroll 1
    for (int it = 0; it < N_FISTA; ++it) {
        float s0 = 0.f, s1 = 0.f, sA = 0.f, sB = 0.f;
#pragma unroll
        for (int s = 0; s < SLOTS; ++s) {
            s0 = fmaf(r0[s], yv[s], s0);
            s1 = fmaf(r1[s], yv[s], s1);
            sA = fmaf(rA[s], yv[s], sA);
            sB = fmaf(rB[s], yv[s], sB);
        }
        s0 = dpp_xor_add<0xB1>(s0); s0 = dpp_xor_add<0x4E>(s0);
        s1 = dpp_xor_add<0xB1>(s1); s1 = dpp_xor_add<0x4E>(s1);
        sA = dpp_xor_add<0xB1>(sA);
        sB = dpp_xor_add<0xB1>(sB);
        const float x0 = fmaf(-0.5f, s0, u0);      // x = -(q + A^T y) * Pinv, q = -2u
        const float x1 = fmaf(-0.5f, s1, u1);
        const float xA = -PINV_S * sA;
        const float xB = -PINV_S * sB;

        const float tk1  = 0.5f * (1.f + __builtin_amdgcn_sqrtf(fmaf(4.f * tk, tk, 1.f)));
        const float beta = (tk - 1.f) * __builtin_amdgcn_rcpf(tk1);
        tk = tk1;

#pragma unroll
        for (int s = 0; s < SLOTS; ++s) {
            const float resid = fmaf(r0[s], x0, fmaf(r1[s], x1,
                                fmaf(rA[s], xA, fmaf(rB[s], xB, -rb[s]))));
            const float ln = fmaxf(fmaf(step, resid, yv[s]), 0.f);
            yv[s] = fmaf(beta, ln - la[s], ln);
            la[s] = ln;
        }
    }

    // ---- Final primal from lambda ----
    float s0 = 0.f, s1 = 0.f;
#pragma unroll
    for (int s = 0; s < SLOTS; ++s) {
        s0 = fmaf(r0[s], la[s], s0);
        s1 = fmaf(r1[s], la[s], s1);
    }
    s0 = dpp_xor_add<0xB1>(s0); s0 = dpp_xor_add<0x4E>(s0);
    s1 = dpp_xor_add<0xB1>(s1); s1 = dpp_xor_add<0x4E>(s1);
    if (sub == 0) {
        out[2 * p]     = fmaf(-0.5f, s0, u0);
        out[2 * p + 1] = fmaf(-0.5f, s1, u1);
    }
}

extern "C" void kernel_launch(void* const* d_in, const int* in_sizes, int n_in,
                              void* d_out, int out_size, void* d_ws, size_t ws_size,
                              hipStream_t stream) {
    const float* u_nom    = (const float*)d_in[0];
    const float* v_cur    = (const float*)d_in[1];
    const float* p_obs    = (const float*)d_in[2];
    const float* obs_mask = (const float*)d_in[3];
    const float* p_ag     = (const float*)d_in[4];
    const float* v_ag     = (const float*)d_in[5];
    const float* ag_mask  = (const float*)d_in[6];
    const float* p_c      = (const float*)d_in[7];
    const float* v_c      = (const float*)d_in[8];
    const float* c_mask   = (const float*)d_in[9];
    float* out = (float*)d_out;

    const int B = in_sizes[0] / 2;
    const long long threads = 4LL * B;
    const int grid = (int)((threads + 255) / 256);
    cbf_fista4<<<grid, 256, 0, stream>>>(
        u_nom, v_cur, p_obs, obs_mask, p_ag, v_ag, ag_mask, p_c, v_c, c_mask, out, B);
}

// Round 3
// 172.440 us; speedup vs baseline: 1.6048x; 1.1245x over previous
//
#include <hip/hip_runtime.h>

// Batched CBF-QP dual FISTA, 4 lanes per problem.
// Row partition (25 active rows; the all-zero "extra" row is provably inert):
//   pair {0,1} owns slack col2 (delta_obs):  lane0: obs0..5
//                                            lane1: obs6..9, slack0, box_a-
//   pair {2,3} owns slack col3 (delta_agent):lane2: nei0..5
//                                            lane3: nei6, slack1, box_a+, box_w-, box_w+, pad
//   col4 (conn row + slack2) is replicated lane-locally in ALL 4 lanes:
//     identical deterministic updates per lane -> no reduction needed; their
//     s0/s1 contributions are added once after the quad DPP reduction.
// s0,s1: full-quad DPP reduce (xor1+xor2). sA: xor1 pair reduce only.

namespace {
constexpr int N_POWER = 30;
constexpr int N_FISTA = 300;
constexpr float PINV_S = 1.0f / 200.0f;  // 1/(2*W_SLACK)
constexpr float BIG = 1000.0f;
constexpr int SLOTS = 6;

constexpr double csqrt(double x) {
    double r = x * 0.5 + 0.5;
    for (int i = 0; i < 50; ++i) r = 0.5 * (r + x / r);
    return r;
}
struct BetaTab { float b[N_FISTA]; };
constexpr BetaTab make_beta() {
    BetaTab t{};
    float tk = 1.0f;
    for (int k = 0; k < N_FISTA; ++k) {
        const float tk1 = 0.5f * (1.0f + (float)csqrt(1.0 + 4.0 * (double)tk * (double)tk));
        t.b[k] = (tk - 1.0f) / tk1;
        tk = tk1;
    }
    return t;
}
}
__constant__ BetaTab BETA = make_beta();

template <int CTRL>
__device__ __forceinline__ float dpp_xor_add(float x) {
    // CTRL: 0xB1 = quad_perm(1,0,3,2) = xor1 ; 0x4E = quad_perm(2,3,0,1) = xor2
    int perm = __builtin_amdgcn_mov_dpp(__float_as_int(x), CTRL, 0xF, 0xF, true);
    return x + __int_as_float(perm);
}

__global__ __launch_bounds__(256) void cbf_fista6(
    const float* __restrict__ u_nom,    // (B,2)
    const float* __restrict__ v_cur,    // (B,1)
    const float* __restrict__ p_obs,    // (B,10,2)
    const float* __restrict__ obs_mask, // (B,10)
    const float* __restrict__ p_ag,     // (B,7,2)
    const float* __restrict__ v_ag,     // (B,7,2)
    const float* __restrict__ ag_mask,  // (B,7)
    const float* __restrict__ p_c,      // (B,1,2)
    const float* __restrict__ v_c,      // (B,1,2)
    const float* __restrict__ c_mask,   // (B,1)
    float* __restrict__ out,            // (B,2)
    int B)
{
    const int t = blockIdx.x * 256 + threadIdx.x;
    const int p = t >> 2;
    const int sub = t & 3;
    if (p >= B) return;

    const float v  = v_cur[p];
    const float u0 = u_nom[2 * p];
    const float u1 = u_nom[2 * p + 1];

    float r0[SLOTS], r1[SLOTS], rA[SLOTS], nb[SLOTS];
#pragma unroll
    for (int s = 0; s < SLOTS; ++s) { r0[s] = 0.f; r1[s] = 0.f; rA[s] = 0.f; nb[s] = -BIG; }

    auto obs_row = [&](int i, int s) {
        const float lx = p_obs[(p * 10 + i) * 2];
        const float ly = p_obs[(p * 10 + i) * 2 + 1];
        const float m  = obs_mask[p * 10 + i];
        const float h   = lx * lx + ly * ly - 0.25f;            // D_OBS^2
        const float hd  = -2.f * lx * v;
        const float rhs = 2.f * v * v + 3.f * hd + 2.f * h;     // DAMP=3, STIFF=2
        r0[s] = 2.f * lx * m;
        r1[s] = 2.f * ly * v * m;
        rA[s] = -m;
        nb[s] = (m > 0.f) ? -rhs : -BIG;
    };
    auto nei_row = [&](int j, int s) {
        const float ax  = p_ag[(p * 7 + j) * 2];
        const float ay  = p_ag[(p * 7 + j) * 2 + 1];
        const float vjx = v_ag[(p * 7 + j) * 2];
        const float vjy = v_ag[(p * 7 + j) * 2 + 1];
        const float m   = ag_mask[p * 7 + j];
        const float h   = ax * ax + ay * ay - 0.64f;            // D_SAFE^2
        const float hd  = -2.f * ax * v + 2.f * (ax * vjx + ay * vjy);
        const float hdd = 2.f * v * v - 2.f * v * vjx
                        + 2.f * (-v * vjx + vjx * vjx + vjy * vjy);
        const float rhs = hdd + 3.f * hd + 2.f * h;             // DAMP_A=3, STIFF_A=2
        r0[s] = 2.f * ax * m;
        r1[s] = (2.f * ay * v - 2.f * ay * vjx + 2.f * ax * vjy) * m;
        rA[s] = -m;
        nb[s] = (m > 0.f) ? -rhs : -BIG;
    };

    if (sub == 0) {
        obs_row(0, 0); obs_row(1, 1); obs_row(2, 2);
        obs_row(3, 3); obs_row(4, 4); obs_row(5, 5);
    } else if (sub == 1) {
        obs_row(6, 0); obs_row(7, 1); obs_row(8, 2); obs_row(9, 3);
        rA[4] = -1.f; nb[4] = 0.f;     // slack0: -delta_obs <= 0 (col2)
        r0[5] = -1.f; nb[5] = -2.f;    // -a <= A_MAX
    } else if (sub == 2) {
        nei_row(0, 0); nei_row(1, 1); nei_row(2, 2);
        nei_row(3, 3); nei_row(4, 4); nei_row(5, 5);
    } else {
        nei_row(6, 0);
        rA[1] = -1.f; nb[1] = 0.f;     // slack1: -delta_agent <= 0 (col3)
        r0[2] =  1.f; nb[2] = -2.f;    //  a <= A_MAX
        r1[3] = -1.f; nb[3] = -1.f;    // -w <= W_MAX
        r1[4] =  1.f; nb[4] = -1.f;    //  w <= W_MAX
        // slot5 = pad (zero coeffs, nb=-BIG): lambda provably stays 0
    }

    // conn + slack2 (col4), replicated identically in every lane
    float c0, c1, cB, ncb;
    {
        const float cx  = p_c[2 * p];
        const float cy  = p_c[2 * p + 1];
        const float cvx = v_c[2 * p];
        const float cvy = v_c[2 * p + 1];
        const float m   = c_mask[p];
        const float h   = 25.f - (cx * cx + cy * cy);           // D_MAX^2
        const float hd  = 2.f * cx * v - 2.f * (cx * cvx + cy * cvy);
        const float hdd = -(2.f * v * v - 2.f * v * cvx
                          + 2.f * (-v * cvx + cvx * cvx + cvy * cvy));
        const float rhs = hdd + 3.f * hd + 2.f * h;             // DAMP_CN=3, STIFF_CN=2
        c0 = -2.f * cx * m;
        c1 = -(2.f * cy * v - 2.f * cy * cvx + 2.f * cx * cvy) * m;
        cB = -m;
        ncb = (m > 0.f) ? -rhs : -BIG;
    }

    // ---- Power iteration: L = lambda_max(A Pinv A^T) ----
    float pv[SLOTS];
#pragma unroll
    for (int s = 0; s < SLOTS; ++s) pv[s] = 1.f;
    float pvC = 1.f, pvS = 1.f;

#pragma unroll 1
    for (int it = 0; it < N_POWER; ++it) {
        float a0 = 0.f, a1 = 0.f, aA = 0.f;
#pragma unroll
        for (int s = 0; s < SLOTS; ++s) {
            a0 = fmaf(r0[s], pv[s], a0);
            a1 = fmaf(r1[s], pv[s], a1);
            aA = fmaf(rA[s], pv[s], aA);
        }
        a0 = dpp_xor_add<0xB1>(a0); a0 = dpp_xor_add<0x4E>(a0);
        a1 = dpp_xor_add<0xB1>(a1); a1 = dpp_xor_add<0x4E>(a1);
        aA = dpp_xor_add<0xB1>(aA);
        a0 = fmaf(c0, pvC, a0);
        a1 = fmaf(c1, pvC, a1);
        const float aC = fmaf(cB, pvC, -pvS);

        const float x0 = 0.5f * a0, x1 = 0.5f * a1;
        const float xA = PINV_S * aA, xC = PINV_S * aC;

        float w[SLOTS], nsq = 0.f;
#pragma unroll
        for (int s = 0; s < SLOTS; ++s) {
            w[s] = fmaf(r0[s], x0, fmaf(r1[s], x1, rA[s] * xA));
            nsq = fmaf(w[s], w[s], nsq);
        }
        nsq = dpp_xor_add<0xB1>(nsq); nsq = dpp_xor_add<0x4E>(nsq);
        const float wC = fmaf(c0, x0, fmaf(c1, x1, cB * xC));
        const float wS = -xC;
        nsq = fmaf(wC, wC, nsq);
        nsq = fmaf(wS, wS, nsq);

        const float inv = __builtin_amdgcn_rcpf(__builtin_amdgcn_sqrtf(nsq) + 1e-12f);
#pragma unroll
        for (int s = 0; s < SLOTS; ++s) pv[s] = w[s] * inv;
        pvC = wC * inv;
        pvS = wS * inv;
    }
    float step;
    {
        float a0 = 0.f, a1 = 0.f, aA = 0.f;
#pragma unroll
        for (int s = 0; s < SLOTS; ++s) {
            a0 = fmaf(r0[s], pv[s], a0);
            a1 = fmaf(r1[s], pv[s], a1);
            aA = fmaf(rA[s], pv[s], aA);
        }
        a0 = dpp_xor_add<0xB1>(a0); a0 = dpp_xor_add<0x4E>(a0);
        a1 = dpp_xor_add<0xB1>(a1); a1 = dpp_xor_add<0x4E>(a1);
        aA = dpp_xor_add<0xB1>(aA);
        a0 = fmaf(c0, pvC, a0);
        a1 = fmaf(c1, pvC, a1);
        const float aC = fmaf(cB, pvC, -pvS);
        // pair sums of slack cols: after xor1, lanes {0,1} hold col2 sum, {2,3} col3
        float tq = aA * aA;
        tq = dpp_xor_add<0x4E>(tq);     // col2^2 + col3^2 in every lane
        const float L = 0.5f * (a0 * a0 + a1 * a1) + PINV_S * (tq + aC * aC);
        step = __builtin_amdgcn_rcpf(L + 1e-6f);
    }

    // ---- FISTA on the dual ----
    float la[SLOTS], yv[SLOTS];
#pragma unroll
    for (int s = 0; s < SLOTS; ++s) { la[s] = 0.f; yv[s] = 0.f; }
    float laC = 0.f, yC = 0.f, laS = 0.f, yS = 0.f;

#pragma unroll 1
    for (int it = 0; it < N_FISTA; ++it) {
        float a0 = 0.f, a1 = 0.f, aA = 0.f;
#pragma unroll
        for (int s = 0; s < SLOTS; ++s) {
            a0 = fmaf(r0[s], yv[s], a0);
            a1 = fmaf(r1[s], yv[s], a1);
            aA = fmaf(rA[s], yv[s], aA);
        }
        a0 = dpp_xor_add<0xB1>(a0); a0 = dpp_xor_add<0x4E>(a0);
        a1 = dpp_xor_add<0xB1>(a1); a1 = dpp_xor_add<0x4E>(a1);
        aA = dpp_xor_add<0xB1>(aA);
        const float sC = fmaf(cB, yC, -yS);

        const float x0 = fmaf(-0.5f, fmaf(c0, yC, a0), u0);  // x = -(q + A^T y)*Pinv
        const float x1 = fmaf(-0.5f, fmaf(c1, yC, a1), u1);
        const float xA = -PINV_S * aA;
        const float xC = -PINV_S * sC;

        const float beta = BETA.b[it];

#pragma unroll
        for (int s = 0; s < SLOTS; ++s) {
            const float resid = fmaf(r0[s], x0, fmaf(r1[s], x1, fmaf(rA[s], xA, nb[s])));
            const float ln = fmaxf(fmaf(step, resid, yv[s]), 0.f);
            yv[s] = fmaf(beta, ln - la[s], ln);
            la[s] = ln;
        }
        {   // conn row
            const float resid = fmaf(c0, x0, fmaf(c1, x1, fmaf(cB, xC, ncb)));
            const float ln = fmaxf(fmaf(step, resid, yC), 0.f);
            yC = fmaf(beta, ln - laC, ln);
            laC = ln;
        }
        {   // slack2 row: resid = -xC
            const float ln = fmaxf(fmaf(step, -xC, yS), 0.f);
            yS = fmaf(beta, ln - laS, ln);
            laS = ln;
        }
    }

    // ---- Final primal from lambda ----
    float a0 = 0.f, a1 = 0.f;
#pragma unroll
    for (int s = 0; s < SLOTS; ++s) {
        a0 = fmaf(r0[s], la[s], a0);
        a1 = fmaf(r1[s], la[s], a1);
    }
    a0 = dpp_xor_add<0xB1>(a0); a0 = dpp_xor_add<0x4E>(a0);
    a1 = dpp_xor_add<0xB1>(a1); a1 = dpp_xor_add<0x4E>(a1);
    a0 = fmaf(c0, laC, a0);
    a1 = fmaf(c1, laC, a1);
    if (sub == 0) {
        out[2 * p]     = fmaf(-0.5f, a0, u0);
        out[2 * p + 1] = fmaf(-0.5f, a1, u1);
    }
}

extern "C" void kernel_launch(void* const* d_in, const int* in_sizes, int n_in,
                              void* d_out, int out_size, void* d_ws, size_t ws_size,
                              hipStream_t stream) {
    const float* u_nom    = (const float*)d_in[0];
    const float* v_cur    = (const float*)d_in[1];
    const float* p_obs    = (const float*)d_in[2];
    const float* obs_mask = (const float*)d_in[3];
    const float* p_ag     = (const float*)d_in[4];
    const float* v_ag     = (const float*)d_in[5];
    const float* ag_mask  = (const float*)d_in[6];
    const float* p_c      = (const float*)d_in[7];
    const float* v_c      = (const float*)d_in[8];
    const float* c_mask   = (const float*)d_in[9];
    float* out = (float*)d_out;

    const int B = in_sizes[0] / 2;
    const long long threads = 4LL * B;
    const int grid = (int)((threads + 255) / 256);
    cbf_fista6<<<grid, 256, 0, stream>>>(
        u_nom, v_cur, p_obs, obs_mask, p_ag, v_ag, ag_mask, p_c, v_c, c_mask, out, B);
}

// Round 4
// 161.592 us; speedup vs baseline: 1.7126x; 1.0671x over previous
//
#include <hip/hip_runtime.h>

// Batched CBF-QP dual FISTA, 4 lanes per problem.
// Row partition (25 active rows; the all-zero "extra" row is provably inert):
//   pair {0,1} owns slack col2 (delta_obs):  lane0: obs0..5
//                                            lane1: obs6..9, slack0, box_a-
//   pair {2,3} owns slack col3 (delta_agent):lane2: nei0..5
//                                            lane3: nei6, slack1, box_a+, box_w-, box_w+, pad
//   col4 (conn row + slack2) replicated lane-locally in ALL 4 lanes (identical
//   deterministic updates; contributions added after the quad DPP reduction).
// FISTA unrolled x2 with lambda ping-pong (no movs); beta loaded in pairs
// (one s_load_dwordx2 per 2 iterations, hoisted); dual fmaf accumulators.

namespace {
constexpr int N_POWER = 30;   // even
constexpr int N_FISTA = 300;  // even
constexpr float PINV_S = 1.0f / 200.0f;  // 1/(2*W_SLACK)
constexpr float BIG = 1000.0f;
constexpr int SLOTS = 6;

constexpr double csqrt(double x) {
    double r = x * 0.5 + 0.5;
    for (int i = 0; i < 50; ++i) r = 0.5 * (r + x / r);
    return r;
}
struct BetaPair { float b0, b1; };
struct BetaTab2 { BetaPair p[N_FISTA / 2]; };
constexpr BetaTab2 make_beta2() {
    BetaTab2 t{};
    float tk = 1.0f;
    for (int k = 0; k < N_FISTA; ++k) {
        const float tk1 = 0.5f * (1.0f + (float)csqrt(1.0 + 4.0 * (double)tk * (double)tk));
        const float bb = (tk - 1.0f) / tk1;
        if (k & 1) t.p[k / 2].b1 = bb; else t.p[k / 2].b0 = bb;
        tk = tk1;
    }
    return t;
}
}
__constant__ BetaTab2 BETA2 = make_beta2();

template <int CTRL>
__device__ __forceinline__ float dpp_xor_add(float x) {
    // CTRL: 0xB1 = quad_perm(1,0,3,2) = xor1 ; 0x4E = quad_perm(2,3,0,1) = xor2
    int perm = __builtin_amdgcn_mov_dpp(__float_as_int(x), CTRL, 0xF, 0xF, true);
    return x + __int_as_float(perm);
}

__global__ __launch_bounds__(256) void cbf_fista7(
    const float* __restrict__ u_nom,    // (B,2)
    const float* __restrict__ v_cur,    // (B,1)
    const float* __restrict__ p_obs,    // (B,10,2)
    const float* __restrict__ obs_mask, // (B,10)
    const float* __restrict__ p_ag,     // (B,7,2)
    const float* __restrict__ v_ag,     // (B,7,2)
    const float* __restrict__ ag_mask,  // (B,7)
    const float* __restrict__ p_c,      // (B,1,2)
    const float* __restrict__ v_c,      // (B,1,2)
    const float* __restrict__ c_mask,   // (B,1)
    float* __restrict__ out,            // (B,2)
    int B)
{
    const int t = blockIdx.x * 256 + threadIdx.x;
    const int p = t >> 2;
    const int sub = t & 3;
    if (p >= B) return;

    const float v  = v_cur[p];
    const float u0 = u_nom[2 * p];
    const float u1 = u_nom[2 * p + 1];

    float r0[SLOTS], r1[SLOTS], rA[SLOTS], nb[SLOTS];
#pragma unroll
    for (int s = 0; s < SLOTS; ++s) { r0[s] = 0.f; r1[s] = 0.f; rA[s] = 0.f; nb[s] = -BIG; }

    auto obs_row = [&](int i, int s) {
        const float lx = p_obs[(p * 10 + i) * 2];
        const float ly = p_obs[(p * 10 + i) * 2 + 1];
        const float m  = obs_mask[p * 10 + i];
        const float h   = lx * lx + ly * ly - 0.25f;            // D_OBS^2
        const float hd  = -2.f * lx * v;
        const float rhs = 2.f * v * v + 3.f * hd + 2.f * h;     // DAMP=3, STIFF=2
        r0[s] = 2.f * lx * m;
        r1[s] = 2.f * ly * v * m;
        rA[s] = -m;
        nb[s] = (m > 0.f) ? -rhs : -BIG;
    };
    auto nei_row = [&](int j, int s) {
        const float ax  = p_ag[(p * 7 + j) * 2];
        const float ay  = p_ag[(p * 7 + j) * 2 + 1];
        const float vjx = v_ag[(p * 7 + j) * 2];
        const float vjy = v_ag[(p * 7 + j) * 2 + 1];
        const float m   = ag_mask[p * 7 + j];
        const float h   = ax * ax + ay * ay - 0.64f;            // D_SAFE^2
        const float hd  = -2.f * ax * v + 2.f * (ax * vjx + ay * vjy);
        const float hdd = 2.f * v * v - 2.f * v * vjx
                        + 2.f * (-v * vjx + vjx * vjx + vjy * vjy);
        const float rhs = hdd + 3.f * hd + 2.f * h;             // DAMP_A=3, STIFF_A=2
        r0[s] = 2.f * ax * m;
        r1[s] = (2.f * ay * v - 2.f * ay * vjx + 2.f * ax * vjy) * m;
        rA[s] = -m;
        nb[s] = (m > 0.f) ? -rhs : -BIG;
    };

    if (sub == 0) {
        obs_row(0, 0); obs_row(1, 1); obs_row(2, 2);
        obs_row(3, 3); obs_row(4, 4); obs_row(5, 5);
    } else if (sub == 1) {
        obs_row(6, 0); obs_row(7, 1); obs_row(8, 2); obs_row(9, 3);
        rA[4] = -1.f; nb[4] = 0.f;     // slack0: -delta_obs <= 0 (col2)
        r0[5] = -1.f; nb[5] = -2.f;    // -a <= A_MAX
    } else if (sub == 2) {
        nei_row(0, 0); nei_row(1, 1); nei_row(2, 2);
        nei_row(3, 3); nei_row(4, 4); nei_row(5, 5);
    } else {
        nei_row(6, 0);
        rA[1] = -1.f; nb[1] = 0.f;     // slack1: -delta_agent <= 0 (col3)
        r0[2] =  1.f; nb[2] = -2.f;    //  a <= A_MAX
        r1[3] = -1.f; nb[3] = -1.f;    // -w <= W_MAX
        r1[4] =  1.f; nb[4] = -1.f;    //  w <= W_MAX
        // slot5 = pad (zero coeffs, nb=-BIG): lambda provably stays 0
    }

    // conn + slack2 (col4), replicated identically in every lane
    float c0, c1, cB, ncb;
    {
        const float cx  = p_c[2 * p];
        const float cy  = p_c[2 * p + 1];
        const float cvx = v_c[2 * p];
        const float cvy = v_c[2 * p + 1];
        const float m   = c_mask[p];
        const float h   = 25.f - (cx * cx + cy * cy);           // D_MAX^2
        const float hd  = 2.f * cx * v - 2.f * (cx * cvx + cy * cvy);
        const float hdd = -(2.f * v * v - 2.f * v * cvx
                          + 2.f * (-v * cvx + cvx * cvx + cvy * cvy));
        const float rhs = hdd + 3.f * hd + 2.f * h;             // DAMP_CN=3, STIFF_CN=2
        c0 = -2.f * cx * m;
        c1 = -(2.f * cy * v - 2.f * cy * cvx + 2.f * cx * cvy) * m;
        cB = -m;
        ncb = (m > 0.f) ? -rhs : -BIG;
    }

    // ---- Power iteration: L = lambda_max(A Pinv A^T), normalize every 2nd ----
    float pv[SLOTS];
#pragma unroll
    for (int s = 0; s < SLOTS; ++s) pv[s] = 1.f;
    float pvC = 1.f, pvS = 1.f;

    auto apply_M = [&]() {
        float a0e = 0.f, a0o = 0.f, a1e = 0.f, a1o = 0.f, aAe = 0.f, aAo = 0.f;
#pragma unroll
        for (int s = 0; s < SLOTS; s += 2) {
            a0e = fmaf(r0[s], pv[s], a0e);
            a1e = fmaf(r1[s], pv[s], a1e);
            aAe = fmaf(rA[s], pv[s], aAe);
            a0o = fmaf(r0[s + 1], pv[s + 1], a0o);
            a1o = fmaf(r1[s + 1], pv[s + 1], a1o);
            aAo = fmaf(rA[s + 1], pv[s + 1], aAo);
        }
        float a0 = a0e + a0o, a1 = a1e + a1o, aA = aAe + aAo;
        a0 = dpp_xor_add<0xB1>(a0); a0 = dpp_xor_add<0x4E>(a0);
        a1 = dpp_xor_add<0xB1>(a1); a1 = dpp_xor_add<0x4E>(a1);
        aA = dpp_xor_add<0xB1>(aA);
        a0 = fmaf(c0, pvC, a0);
        a1 = fmaf(c1, pvC, a1);
        const float aC = fmaf(cB, pvC, -pvS);
        const float x0 = 0.5f * a0, x1 = 0.5f * a1;
        const float xA = PINV_S * aA, xC = PINV_S * aC;
#pragma unroll
        for (int s = 0; s < SLOTS; ++s)
            pv[s] = fmaf(r0[s], x0, fmaf(r1[s], x1, rA[s] * xA));
        pvC = fmaf(c0, x0, fmaf(c1, x1, cB * xC));
        pvS = -xC;
    };

#pragma unroll 1
    for (int o = 0; o < N_POWER / 2; ++o) {
        apply_M();
        apply_M();
        float nsq = 0.f;
#pragma unroll
        for (int s = 0; s < SLOTS; ++s) nsq = fmaf(pv[s], pv[s], nsq);
        nsq = dpp_xor_add<0xB1>(nsq); nsq = dpp_xor_add<0x4E>(nsq);
        nsq = fmaf(pvC, pvC, fmaf(pvS, pvS, nsq));
        const float inv = __builtin_amdgcn_rsqf(nsq + 1e-24f);
#pragma unroll
        for (int s = 0; s < SLOTS; ++s) pv[s] *= inv;
        pvC *= inv;
        pvS *= inv;
    }
    float step;
    {
        float a0 = 0.f, a1 = 0.f, aA = 0.f;
#pragma unroll
        for (int s = 0; s < SLOTS; ++s) {
            a0 = fmaf(r0[s], pv[s], a0);
            a1 = fmaf(r1[s], pv[s], a1);
            aA = fmaf(rA[s], pv[s], aA);
        }
        a0 = dpp_xor_add<0xB1>(a0); a0 = dpp_xor_add<0x4E>(a0);
        a1 = dpp_xor_add<0xB1>(a1); a1 = dpp_xor_add<0x4E>(a1);
        aA = dpp_xor_add<0xB1>(aA);
        a0 = fmaf(c0, pvC, a0);
        a1 = fmaf(c1, pvC, a1);
        const float aC = fmaf(cB, pvC, -pvS);
        // pair sums of slack cols: after xor1, lanes {0,1} hold col2, {2,3} col3
        float tq = aA * aA;
        tq = dpp_xor_add<0x4E>(tq);     // col2^2 + col3^2 in every lane
        const float L = 0.5f * (a0 * a0 + a1 * a1) + PINV_S * (tq + aC * aC);
        step = __builtin_amdgcn_rcpf(L + 1e-6f);
    }

    // ---- FISTA on the dual, unrolled x2 with lambda ping-pong ----
    float laE[SLOTS], laO[SLOTS], yv[SLOTS];
#pragma unroll
    for (int s = 0; s < SLOTS; ++s) { laE[s] = 0.f; laO[s] = 0.f; yv[s] = 0.f; }
    float laCE = 0.f, laCO = 0.f, yC = 0.f;
    float laSE = 0.f, laSO = 0.f, yS = 0.f;

    auto half_step = [&](float (&ln_)[SLOTS], const float (&lp_)[SLOTS],
                         float& lnC, float lpC, float& lnS, float lpS,
                         float beta) {
        float a0e = 0.f, a0o = 0.f, a1e = 0.f, a1o = 0.f, aAe = 0.f, aAo = 0.f;
#pragma unroll
        for (int s = 0; s < SLOTS; s += 2) {
            a0e = fmaf(r0[s], yv[s], a0e);
            a1e = fmaf(r1[s], yv[s], a1e);
            aAe = fmaf(rA[s], yv[s], aAe);
            a0o = fmaf(r0[s + 1], yv[s + 1], a0o);
            a1o = fmaf(r1[s + 1], yv[s + 1], a1o);
            aAo = fmaf(rA[s + 1], yv[s + 1], aAo);
        }
        float a0 = a0e + a0o, a1 = a1e + a1o, aA = aAe + aAo;
        a0 = dpp_xor_add<0xB1>(a0); a0 = dpp_xor_add<0x4E>(a0);
        a1 = dpp_xor_add<0xB1>(a1); a1 = dpp_xor_add<0x4E>(a1);
        aA = dpp_xor_add<0xB1>(aA);
        const float sC = fmaf(cB, yC, -yS);
        const float x0 = fmaf(-0.5f, fmaf(c0, yC, a0), u0);  // x = -(q + A^T y)*Pinv
        const float x1 = fmaf(-0.5f, fmaf(c1, yC, a1), u1);
        const float xA = -PINV_S * aA;
        const float xC = -PINV_S * sC;
#pragma unroll
        for (int s = 0; s < SLOTS; ++s) {
            const float resid = fmaf(r0[s], x0, fmaf(r1[s], x1, fmaf(rA[s], xA, nb[s])));
            const float l = fmaxf(fmaf(step, resid, yv[s]), 0.f);
            yv[s] = fmaf(beta, l - lp_[s], l);
            ln_[s] = l;
        }
        {   // conn row
            const float resid = fmaf(c0, x0, fmaf(c1, x1, fmaf(cB, xC, ncb)));
            const float l = fmaxf(fmaf(step, resid, yC), 0.f);
            yC = fmaf(beta, l - lpC, l);
            lnC = l;
        }
        {   // slack2 row: resid = -xC
            const float l = fmaxf(fmaf(step, -xC, yS), 0.f);
            yS = fmaf(beta, l - lpS, l);
            lnS = l;
        }
    };

#pragma unroll 1
    for (int o = 0; o < N_FISTA / 2; ++o) {
        const float b0 = BETA2.p[o].b0;   // one s_load_dwordx2, hoisted
        const float b1 = BETA2.p[o].b1;
        half_step(laE, laO, laCE, laCO, laSE, laSO, b0);  // it=2o   writes E
        half_step(laO, laE, laCO, laCE, laSO, laSE, b1);  // it=2o+1 writes O
    }

    // ---- Final primal from lambda (last write was laO / laCO) ----
    float a0 = 0.f, a1 = 0.f;
#pragma unroll
    for (int s = 0; s < SLOTS; ++s) {
        a0 = fmaf(r0[s], laO[s], a0);
        a1 = fmaf(r1[s], laO[s], a1);
    }
    a0 = dpp_xor_add<0xB1>(a0); a0 = dpp_xor_add<0x4E>(a0);
    a1 = dpp_xor_add<0xB1>(a1); a1 = dpp_xor_add<0x4E>(a1);
    a0 = fmaf(c0, laCO, a0);
    a1 = fmaf(c1, laCO, a1);
    if (sub == 0) {
        out[2 * p]     = fmaf(-0.5f, a0, u0);
        out[2 * p + 1] = fmaf(-0.5f, a1, u1);
    }
}

extern "C" void kernel_launch(void* const* d_in, const int* in_sizes, int n_in,
                              void* d_out, int out_size, void* d_ws, size_t ws_size,
                              hipStream_t stream) {
    const float* u_nom    = (const float*)d_in[0];
    const float* v_cur    = (const float*)d_in[1];
    const float* p_obs    = (const float*)d_in[2];
    const float* obs_mask = (const float*)d_in[3];
    const float* p_ag     = (const float*)d_in[4];
    const float* v_ag     = (const float*)d_in[5];
    const float* ag_mask  = (const float*)d_in[6];
    const float* p_c      = (const float*)d_in[7];
    const float* v_c      = (const float*)d_in[8];
    const float* c_mask   = (const float*)d_in[9];
    float* out = (float*)d_out;

    const int B = in_sizes[0] / 2;
    const long long threads = 4LL * B;
    const int grid = (int)((threads + 255) / 256);
    cbf_fista7<<<grid, 256, 0, stream>>>(
        u_nom, v_cur, p_obs, obs_mask, p_ag, v_ag, ag_mask, p_c, v_c, c_mask, out, B);
}

// Round 5
// 159.273 us; speedup vs baseline: 1.7375x; 1.0146x over previous
//
#include <hip/hip_runtime.h>

// Batched CBF-QP dual FISTA, 4 lanes per problem.
// Row partition (25 active rows; the all-zero "extra" row is provably inert):
//   pair {0,1} owns slack col2 (delta_obs):  lane0: obs0..5
//                                            lane1: obs6..9, slack0, box_a-
//   pair {2,3} owns slack col3 (delta_agent):lane2: nei0..5
//                                            lane3: nei6, slack1, box_a+, box_w-, box_w+, pad
//   col4 (conn row + slack2) replicated lane-locally in ALL 4 lanes (identical
//   deterministic updates; contributions added after the quad DPP reduction).
// Round-5 changes:
//   * __launch_bounds__(256,2): grid gives exactly 2 waves/SIMD, so grant the
//     full 256-VGPR budget -> no scratch spilling of loop state.
//   * dual variable kept in z = y/step scale: removes the step-fmaf per row.
//   * FISTA unrolled x4; one s_load_dwordx4 of beta per 4 iterations.

namespace {
constexpr int N_POWER = 30;   // even
constexpr int N_FISTA = 300;  // divisible by 4
constexpr float PINV_S = 1.0f / 200.0f;  // 1/(2*W_SLACK)
constexpr float BIG = 1000.0f;
constexpr int SLOTS = 6;

constexpr double csqrt(double x) {
    double r = x * 0.5 + 0.5;
    for (int i = 0; i < 50; ++i) r = 0.5 * (r + x / r);
    return r;
}
struct alignas(16) BetaQuad { float b[4]; };
struct BetaTab4 { BetaQuad q[N_FISTA / 4]; };
constexpr BetaTab4 make_beta4() {
    BetaTab4 t{};
    float tk = 1.0f;
    for (int k = 0; k < N_FISTA; ++k) {
        const float tk1 = 0.5f * (1.0f + (float)csqrt(1.0 + 4.0 * (double)tk * (double)tk));
        t.q[k / 4].b[k % 4] = (tk - 1.0f) / tk1;
        tk = tk1;
    }
    return t;
}
}
__constant__ BetaTab4 BETA4 = make_beta4();

template <int CTRL>
__device__ __forceinline__ float dpp_xor_add(float x) {
    // CTRL: 0xB1 = quad_perm(1,0,3,2) = xor1 ; 0x4E = quad_perm(2,3,0,1) = xor2
    int perm = __builtin_amdgcn_mov_dpp(__float_as_int(x), CTRL, 0xF, 0xF, true);
    return x + __int_as_float(perm);
}

__global__ __launch_bounds__(256, 2) void cbf_fista8(
    const float* __restrict__ u_nom,    // (B,2)
    const float* __restrict__ v_cur,    // (B,1)
    const float* __restrict__ p_obs,    // (B,10,2)
    const float* __restrict__ obs_mask, // (B,10)
    const float* __restrict__ p_ag,     // (B,7,2)
    const float* __restrict__ v_ag,     // (B,7,2)
    const float* __restrict__ ag_mask,  // (B,7)
    const float* __restrict__ p_c,      // (B,1,2)
    const float* __restrict__ v_c,      // (B,1,2)
    const float* __restrict__ c_mask,   // (B,1)
    float* __restrict__ out,            // (B,2)
    int B)
{
    const int t = blockIdx.x * 256 + threadIdx.x;
    const int p = t >> 2;
    const int sub = t & 3;
    if (p >= B) return;

    const float v  = v_cur[p];
    const float u0 = u_nom[2 * p];
    const float u1 = u_nom[2 * p + 1];

    float r0[SLOTS], r1[SLOTS], rA[SLOTS], nb[SLOTS];
#pragma unroll
    for (int s = 0; s < SLOTS; ++s) { r0[s] = 0.f; r1[s] = 0.f; rA[s] = 0.f; nb[s] = -BIG; }

    auto obs_row = [&](int i, int s) {
        const float lx = p_obs[(p * 10 + i) * 2];
        const float ly = p_obs[(p * 10 + i) * 2 + 1];
        const float m  = obs_mask[p * 10 + i];
        const float h   = lx * lx + ly * ly - 0.25f;            // D_OBS^2
        const float hd  = -2.f * lx * v;
        const float rhs = 2.f * v * v + 3.f * hd + 2.f * h;     // DAMP=3, STIFF=2
        r0[s] = 2.f * lx * m;
        r1[s] = 2.f * ly * v * m;
        rA[s] = -m;
        nb[s] = (m > 0.f) ? -rhs : -BIG;
    };
    auto nei_row = [&](int j, int s) {
        const float ax  = p_ag[(p * 7 + j) * 2];
        const float ay  = p_ag[(p * 7 + j) * 2 + 1];
        const float vjx = v_ag[(p * 7 + j) * 2];
        const float vjy = v_ag[(p * 7 + j) * 2 + 1];
        const float m   = ag_mask[p * 7 + j];
        const float h   = ax * ax + ay * ay - 0.64f;            // D_SAFE^2
        const float hd  = -2.f * ax * v + 2.f * (ax * vjx + ay * vjy);
        const float hdd = 2.f * v * v - 2.f * v * vjx
                        + 2.f * (-v * vjx + vjx * vjx + vjy * vjy);
        const float rhs = hdd + 3.f * hd + 2.f * h;             // DAMP_A=3, STIFF_A=2
        r0[s] = 2.f * ax * m;
        r1[s] = (2.f * ay * v - 2.f * ay * vjx + 2.f * ax * vjy) * m;
        rA[s] = -m;
        nb[s] = (m > 0.f) ? -rhs : -BIG;
    };

    if (sub == 0) {
        obs_row(0, 0); obs_row(1, 1); obs_row(2, 2);
        obs_row(3, 3); obs_row(4, 4); obs_row(5, 5);
    } else if (sub == 1) {
        obs_row(6, 0); obs_row(7, 1); obs_row(8, 2); obs_row(9, 3);
        rA[4] = -1.f; nb[4] = 0.f;     // slack0: -delta_obs <= 0 (col2)
        r0[5] = -1.f; nb[5] = -2.f;    // -a <= A_MAX
    } else if (sub == 2) {
        nei_row(0, 0); nei_row(1, 1); nei_row(2, 2);
        nei_row(3, 3); nei_row(4, 4); nei_row(5, 5);
    } else {
        nei_row(6, 0);
        rA[1] = -1.f; nb[1] = 0.f;     // slack1: -delta_agent <= 0 (col3)
        r0[2] =  1.f; nb[2] = -2.f;    //  a <= A_MAX
        r1[3] = -1.f; nb[3] = -1.f;    // -w <= W_MAX
        r1[4] =  1.f; nb[4] = -1.f;    //  w <= W_MAX
        // slot5 = pad (zero coeffs, nb=-BIG): lambda provably stays 0
    }

    // conn + slack2 (col4), replicated identically in every lane
    float c0, c1, cB, ncb;
    {
        const float cx  = p_c[2 * p];
        const float cy  = p_c[2 * p + 1];
        const float cvx = v_c[2 * p];
        const float cvy = v_c[2 * p + 1];
        const float m   = c_mask[p];
        const float h   = 25.f - (cx * cx + cy * cy);           // D_MAX^2
        const float hd  = 2.f * cx * v - 2.f * (cx * cvx + cy * cvy);
        const float hdd = -(2.f * v * v - 2.f * v * cvx
                          + 2.f * (-v * cvx + cvx * cvx + cvy * cvy));
        const float rhs = hdd + 3.f * hd + 2.f * h;             // DAMP_CN=3, STIFF_CN=2
        c0 = -2.f * cx * m;
        c1 = -(2.f * cy * v - 2.f * cy * cvx + 2.f * cx * cvy) * m;
        cB = -m;
        ncb = (m > 0.f) ? -rhs : -BIG;
    }

    // ---- Power iteration: L = lambda_max(A Pinv A^T), normalize every 2nd ----
    float pv[SLOTS];
#pragma unroll
    for (int s = 0; s < SLOTS; ++s) pv[s] = 1.f;
    float pvC = 1.f, pvS = 1.f;

    auto apply_M = [&]() {
        float a0e = 0.f, a0o = 0.f, a1e = 0.f, a1o = 0.f, aAe = 0.f, aAo = 0.f;
#pragma unroll
        for (int s = 0; s < SLOTS; s += 2) {
            a0e = fmaf(r0[s], pv[s], a0e);
            a1e = fmaf(r1[s], pv[s], a1e);
            aAe = fmaf(rA[s], pv[s], aAe);
            a0o = fmaf(r0[s + 1], pv[s + 1], a0o);
            a1o = fmaf(r1[s + 1], pv[s + 1], a1o);
            aAo = fmaf(rA[s + 1], pv[s + 1], aAo);
        }
        float a0 = a0e + a0o, a1 = a1e + a1o, aA = aAe + aAo;
        a0 = dpp_xor_add<0xB1>(a0); a0 = dpp_xor_add<0x4E>(a0);
        a1 = dpp_xor_add<0xB1>(a1); a1 = dpp_xor_add<0x4E>(a1);
        aA = dpp_xor_add<0xB1>(aA);
        a0 = fmaf(c0, pvC, a0);
        a1 = fmaf(c1, pvC, a1);
        const float aC = fmaf(cB, pvC, -pvS);
        const float x0 = 0.5f * a0, x1 = 0.5f * a1;
        const float xA = PINV_S * aA, xC = PINV_S * aC;
#pragma unroll
        for (int s = 0; s < SLOTS; ++s)
            pv[s] = fmaf(r0[s], x0, fmaf(r1[s], x1, rA[s] * xA));
        pvC = fmaf(c0, x0, fmaf(c1, x1, cB * xC));
        pvS = -xC;
    };

#pragma unroll 1
    for (int o = 0; o < N_POWER / 2; ++o) {
        apply_M();
        apply_M();
        float nsq = 0.f;
#pragma unroll
        for (int s = 0; s < SLOTS; ++s) nsq = fmaf(pv[s], pv[s], nsq);
        nsq = dpp_xor_add<0xB1>(nsq); nsq = dpp_xor_add<0x4E>(nsq);
        nsq = fmaf(pvC, pvC, fmaf(pvS, pvS, nsq));
        const float inv = __builtin_amdgcn_rsqf(nsq + 1e-24f);
#pragma unroll
        for (int s = 0; s < SLOTS; ++s) pv[s] *= inv;
        pvC *= inv;
        pvS *= inv;
    }
    float nsh, pA;   // -step/2, -step*PINV_S
    {
        float a0 = 0.f, a1 = 0.f, aA = 0.f;
#pragma unroll
        for (int s = 0; s < SLOTS; ++s) {
            a0 = fmaf(r0[s], pv[s], a0);
            a1 = fmaf(r1[s], pv[s], a1);
            aA = fmaf(rA[s], pv[s], aA);
        }
        a0 = dpp_xor_add<0xB1>(a0); a0 = dpp_xor_add<0x4E>(a0);
        a1 = dpp_xor_add<0xB1>(a1); a1 = dpp_xor_add<0x4E>(a1);
        aA = dpp_xor_add<0xB1>(aA);
        a0 = fmaf(c0, pvC, a0);
        a1 = fmaf(c1, pvC, a1);
        const float aC = fmaf(cB, pvC, -pvS);
        // pair sums of slack cols: after xor1, lanes {0,1} hold col2, {2,3} col3
        float tq = aA * aA;
        tq = dpp_xor_add<0x4E>(tq);     // col2^2 + col3^2 in every lane
        const float L = 0.5f * (a0 * a0 + a1 * a1) + PINV_S * (tq + aC * aC);
        const float step = __builtin_amdgcn_rcpf(L + 1e-6f);
        nsh = -0.5f * step;
        pA  = -PINV_S * step;
    }

    // ---- FISTA on the dual, z = y/step scale, unrolled x4, lambda ping-pong ----
    float laE[SLOTS], laO[SLOTS], zv[SLOTS];
#pragma unroll
    for (int s = 0; s < SLOTS; ++s) { laE[s] = 0.f; laO[s] = 0.f; zv[s] = 0.f; }
    float laCE = 0.f, laCO = 0.f, zC = 0.f;
    float laSE = 0.f, laSO = 0.f, zS = 0.f;

    auto half_step = [&](float (&ln_)[SLOTS], const float (&lp_)[SLOTS],
                         float& lnC, float lpC, float& lnS, float lpS,
                         float beta) {
        float a0e = 0.f, a0o = 0.f, a1e = 0.f, a1o = 0.f, aAe = 0.f, aAo = 0.f;
#pragma unroll
        for (int s = 0; s < SLOTS; s += 2) {
            a0e = fmaf(r0[s], zv[s], a0e);
            a1e = fmaf(r1[s], zv[s], a1e);
            aAe = fmaf(rA[s], zv[s], aAe);
            a0o = fmaf(r0[s + 1], zv[s + 1], a0o);
            a1o = fmaf(r1[s + 1], zv[s + 1], a1o);
            aAo = fmaf(rA[s + 1], zv[s + 1], aAo);
        }
        float a0 = a0e + a0o, a1 = a1e + a1o, aA = aAe + aAo;
        a0 = dpp_xor_add<0xB1>(a0); a0 = dpp_xor_add<0x4E>(a0);
        a1 = dpp_xor_add<0xB1>(a1); a1 = dpp_xor_add<0x4E>(a1);
        aA = dpp_xor_add<0xB1>(aA);
        const float sCz = fmaf(cB, zC, -zS);
        const float x0 = fmaf(nsh, fmaf(c0, zC, a0), u0);  // x = -(q + A^T y)*Pinv
        const float x1 = fmaf(nsh, fmaf(c1, zC, a1), u1);
        const float xA = pA * aA;
        const float xC = pA * sCz;
#pragma unroll
        for (int s = 0; s < SLOTS; ++s) {
            const float resid = fmaf(r0[s], x0, fmaf(r1[s], x1, fmaf(rA[s], xA, nb[s])));
            const float l = fmaxf(zv[s] + resid, 0.f);
            zv[s] = fmaf(beta, l - lp_[s], l);
            ln_[s] = l;
        }
        {   // conn row
            const float resid = fmaf(c0, x0, fmaf(c1, x1, fmaf(cB, xC, ncb)));
            const float l = fmaxf(zC + resid, 0.f);
            zC = fmaf(beta, l - lpC, l);
            lnC = l;
        }
        {   // slack2 row: resid = -xC
            const float l = fmaxf(zS - xC, 0.f);
            zS = fmaf(beta, l - lpS, l);
            lnS = l;
        }
    };

#pragma unroll 1
    for (int o = 0; o < N_FISTA / 4; ++o) {
        const BetaQuad bq = BETA4.q[o];   // one s_load_dwordx4 per 4 iterations
        half_step(laE, laO, laCE, laCO, laSE, laSO, bq.b[0]);
        half_step(laO, laE, laCO, laCE, laSO, laSE, bq.b[1]);
        half_step(laE, laO, laCE, laCO, laSE, laSO, bq.b[2]);
        half_step(laO, laE, laCO, laCE, laSO, laSE, bq.b[3]);
    }

    // ---- Final primal from lambda = step*Lambda (last write was laO / laCO) ----
    float a0 = 0.f, a1 = 0.f;
#pragma unroll
    for (int s = 0; s < SLOTS; ++s) {
        a0 = fmaf(r0[s], laO[s], a0);
        a1 = fmaf(r1[s], laO[s], a1);
    }
    a0 = dpp_xor_add<0xB1>(a0); a0 = dpp_xor_add<0x4E>(a0);
    a1 = dpp_xor_add<0xB1>(a1); a1 = dpp_xor_add<0x4E>(a1);
    a0 = fmaf(c0, laCO, a0);
    a1 = fmaf(c1, laCO, a1);
    if (sub == 0) {
        out[2 * p]     = fmaf(nsh, a0, u0);
        out[2 * p + 1] = fmaf(nsh, a1, u1);
    }
}

extern "C" void kernel_launch(void* const* d_in, const int* in_sizes, int n_in,
                              void* d_out, int out_size, void* d_ws, size_t ws_size,
                              hipStream_t stream) {
    const float* u_nom    = (const float*)d_in[0];
    const float* v_cur    = (const float*)d_in[1];
    const float* p_obs    = (const float*)d_in[2];
    const float* obs_mask = (const float*)d_in[3];
    const float* p_ag     = (const float*)d_in[4];
    const float* v_ag     = (const float*)d_in[5];
    const float* ag_mask  = (const float*)d_in[6];
    const float* p_c      = (const float*)d_in[7];
    const float* v_c      = (const float*)d_in[8];
    const float* c_mask   = (const float*)d_in[9];
    float* out = (float*)d_out;

    const int B = in_sizes[0] / 2;
    const long long threads = 4LL * B;
    const int grid = (int)((threads + 255) / 256);
    cbf_fista8<<<grid, 256, 0, stream>>>(
        u_nom, v_cur, p_obs, obs_mask, p_ag, v_ag, ag_mask, p_c, v_c, c_mask, out, B);
}

// Round 6
// 146.631 us; speedup vs baseline: 1.8873x; 1.0862x over previous
//
#include <hip/hip_runtime.h>

// Batched CBF-QP dual FISTA, 4 lanes per problem, PACKED fp32 (v_pk_fma_f32).
// Row partition (25 active rows; all-zero "extra" row provably inert):
//   pair {0,1} owns slack col2: lane0 obs0..5; lane1 obs6..9, slack0, box_a-
//   pair {2,3} owns slack col3: lane2 nei0..5; lane3 nei6, slack1, box_a+, box_w-, box_w+, pad
//   col4 (conn + slack2) replicated in all 4 lanes, PACKED as one v2 row:
//     coeffs {c0,0},{c1,0},{cB,-1},{ncb,0} reproduce both residuals.
// 6 scalar slots -> 3 float2 slots; all row math in VOP3P packed fp32.
// Sustained-clock note (r5 post-mortem): fp32-VALU-saturated kernels run at
// ~1.6 GHz on MI355X (m07: 103/157.3 TF), so wins come from instr count.

typedef float v2f __attribute__((ext_vector_type(2)));

namespace {
constexpr int N_POWER = 30;   // even
constexpr int N_FISTA = 300;  // even
constexpr float PINV_S = 1.0f / 200.0f;  // 1/(2*W_SLACK)
constexpr float BIG = 1000.0f;

constexpr double csqrt(double x) {
    double r = x * 0.5 + 0.5;
    for (int i = 0; i < 50; ++i) r = 0.5 * (r + x / r);
    return r;
}
// beta stored pre-duplicated: {b0,b0,b1,b1} per quad -> packed operand needs no splat movs
struct alignas(16) BQuadDup { float b[4]; };
struct BetaTabD { BQuadDup q[N_FISTA / 2]; };
constexpr BetaTabD make_betad() {
    BetaTabD t{};
    float tk = 1.0f;
    for (int k = 0; k < N_FISTA; ++k) {
        const float tk1 = 0.5f * (1.0f + (float)csqrt(1.0 + 4.0 * (double)tk * (double)tk));
        const float bb = (tk - 1.0f) / tk1;
        t.q[k / 2].b[(k % 2) * 2]     = bb;
        t.q[k / 2].b[(k % 2) * 2 + 1] = bb;
        tk = tk1;
    }
    return t;
}
}
__constant__ BetaTabD BETAD = make_betad();

template <int CTRL>
__device__ __forceinline__ float dpp_xor_add(float x) {
    // CTRL: 0xB1 = quad_perm(1,0,3,2) = xor1 ; 0x4E = quad_perm(2,3,0,1) = xor2
    int perm = __builtin_amdgcn_mov_dpp(__float_as_int(x), CTRL, 0xF, 0xF, true);
    return x + __int_as_float(perm);
}

__device__ __forceinline__ v2f vfma(v2f a, v2f b, v2f c) {
    return __builtin_elementwise_fma(a, b, c);
}
__device__ __forceinline__ v2f vmax0(v2f a) {
    const v2f z = {0.f, 0.f};
    return __builtin_elementwise_max(a, z);
}

__global__ __launch_bounds__(256, 2) void cbf_fista9(
    const float* __restrict__ u_nom,    // (B,2)
    const float* __restrict__ v_cur,    // (B,1)
    const float* __restrict__ p_obs,    // (B,10,2)
    const float* __restrict__ obs_mask, // (B,10)
    const float* __restrict__ p_ag,     // (B,7,2)
    const float* __restrict__ v_ag,     // (B,7,2)
    const float* __restrict__ ag_mask,  // (B,7)
    const float* __restrict__ p_c,      // (B,1,2)
    const float* __restrict__ v_c,      // (B,1,2)
    const float* __restrict__ c_mask,   // (B,1)
    float* __restrict__ out,            // (B,2)
    int B)
{
    const int t = blockIdx.x * 256 + threadIdx.x;
    const int p = t >> 2;
    const int sub = t & 3;
    if (p >= B) return;

    const float v  = v_cur[p];
    const float u0 = u_nom[2 * p];
    const float u1 = u_nom[2 * p + 1];

    float r0[6], r1[6], rA[6], nb[6];
#pragma unroll
    for (int s = 0; s < 6; ++s) { r0[s] = 0.f; r1[s] = 0.f; rA[s] = 0.f; nb[s] = -BIG; }

    auto obs_row = [&](int i, int s) {
        const float lx = p_obs[(p * 10 + i) * 2];
        const float ly = p_obs[(p * 10 + i) * 2 + 1];
        const float m  = obs_mask[p * 10 + i];
        const float h   = lx * lx + ly * ly - 0.25f;            // D_OBS^2
        const float hd  = -2.f * lx * v;
        const float rhs = 2.f * v * v + 3.f * hd + 2.f * h;     // DAMP=3, STIFF=2
        r0[s] = 2.f * lx * m;
        r1[s] = 2.f * ly * v * m;
        rA[s] = -m;
        nb[s] = (m > 0.f) ? -rhs : -BIG;
    };
    auto nei_row = [&](int j, int s) {
        const float ax  = p_ag[(p * 7 + j) * 2];
        const float ay  = p_ag[(p * 7 + j) * 2 + 1];
        const float vjx = v_ag[(p * 7 + j) * 2];
        const float vjy = v_ag[(p * 7 + j) * 2 + 1];
        const float m   = ag_mask[p * 7 + j];
        const float h   = ax * ax + ay * ay - 0.64f;            // D_SAFE^2
        const float hd  = -2.f * ax * v + 2.f * (ax * vjx + ay * vjy);
        const float hdd = 2.f * v * v - 2.f * v * vjx
                        + 2.f * (-v * vjx + vjx * vjx + vjy * vjy);
        const float rhs = hdd + 3.f * hd + 2.f * h;             // DAMP_A=3, STIFF_A=2
        r0[s] = 2.f * ax * m;
        r1[s] = (2.f * ay * v - 2.f * ay * vjx + 2.f * ax * vjy) * m;
        rA[s] = -m;
        nb[s] = (m > 0.f) ? -rhs : -BIG;
    };

    if (sub == 0) {
        obs_row(0, 0); obs_row(1, 1); obs_row(2, 2);
        obs_row(3, 3); obs_row(4, 4); obs_row(5, 5);
    } else if (sub == 1) {
        obs_row(6, 0); obs_row(7, 1); obs_row(8, 2); obs_row(9, 3);
        rA[4] = -1.f; nb[4] = 0.f;     // slack0: -delta_obs <= 0 (col2)
        r0[5] = -1.f; nb[5] = -2.f;    // -a <= A_MAX
    } else if (sub == 2) {
        nei_row(0, 0); nei_row(1, 1); nei_row(2, 2);
        nei_row(3, 3); nei_row(4, 4); nei_row(5, 5);
    } else {
        nei_row(6, 0);
        rA[1] = -1.f; nb[1] = 0.f;     // slack1: -delta_agent <= 0 (col3)
        r0[2] =  1.f; nb[2] = -2.f;    //  a <= A_MAX
        r1[3] = -1.f; nb[3] = -1.f;    // -w <= W_MAX
        r1[4] =  1.f; nb[4] = -1.f;    //  w <= W_MAX
        // slot5 = pad (zero coeffs, nb=-BIG): lambda provably stays 0
    }

    // pack 6 scalar slots into 3 packed slots
    v2f R0[3], R1[3], RA[3], NB[3];
#pragma unroll
    for (int k = 0; k < 3; ++k) {
        R0[k] = v2f{r0[2 * k], r0[2 * k + 1]};
        R1[k] = v2f{r1[2 * k], r1[2 * k + 1]};
        RA[k] = v2f{rA[2 * k], rA[2 * k + 1]};
        NB[k] = v2f{nb[2 * k], nb[2 * k + 1]};
    }

    // conn + slack2 (col4), replicated in every lane, packed as one v2 row
    float c0, c1, cB;
    v2f C0v, C1v, CB2, NCBv;
    {
        const float cx  = p_c[2 * p];
        const float cy  = p_c[2 * p + 1];
        const float cvx = v_c[2 * p];
        const float cvy = v_c[2 * p + 1];
        const float m   = c_mask[p];
        const float h   = 25.f - (cx * cx + cy * cy);           // D_MAX^2
        const float hd  = 2.f * cx * v - 2.f * (cx * cvx + cy * cvy);
        const float hdd = -(2.f * v * v - 2.f * v * cvx
                          + 2.f * (-v * cvx + cvx * cvx + cvy * cvy));
        const float rhs = hdd + 3.f * hd + 2.f * h;             // DAMP_CN=3, STIFF_CN=2
        c0 = -2.f * cx * m;
        c1 = -(2.f * cy * v - 2.f * cy * cvx + 2.f * cx * cvy) * m;
        cB = -m;
        const float ncb = (m > 0.f) ? -rhs : -BIG;
        C0v  = v2f{c0, 0.f};
        C1v  = v2f{c1, 0.f};
        CB2  = v2f{cB, -1.f};
        NCBv = v2f{ncb, 0.f};
    }

    // ---- Power iteration: L = lambda_max(A Pinv A^T), normalize every 2nd ----
    v2f PV[3];
#pragma unroll
    for (int k = 0; k < 3; ++k) PV[k] = v2f{1.f, 1.f};
    float pvC = 1.f, pvS = 1.f;

    auto apply_M = [&]() {
        v2f A0 = vfma(R0[0], PV[0], vfma(R0[1], PV[1], R0[2] * PV[2]));
        v2f A1 = vfma(R1[0], PV[0], vfma(R1[1], PV[1], R1[2] * PV[2]));
        v2f AA = vfma(RA[0], PV[0], vfma(RA[1], PV[1], RA[2] * PV[2]));
        float a0 = A0.x + A0.y, a1 = A1.x + A1.y, aA = AA.x + AA.y;
        a0 = dpp_xor_add<0xB1>(a0); a0 = dpp_xor_add<0x4E>(a0);
        a1 = dpp_xor_add<0xB1>(a1); a1 = dpp_xor_add<0x4E>(a1);
        aA = dpp_xor_add<0xB1>(aA);
        a0 = fmaf(c0, pvC, a0);
        a1 = fmaf(c1, pvC, a1);
        const float aC = fmaf(cB, pvC, -pvS);
        const float x0 = 0.5f * a0, x1 = 0.5f * a1;
        const float xA = PINV_S * aA, xC = PINV_S * aC;
        const v2f X0 = {x0, x0}, X1 = {x1, x1}, XA = {xA, xA};
#pragma unroll
        for (int k = 0; k < 3; ++k)
            PV[k] = vfma(R0[k], X0, vfma(R1[k], X1, RA[k] * XA));
        pvC = fmaf(c0, x0, fmaf(c1, x1, cB * xC));
        pvS = -xC;
    };

#pragma unroll 1
    for (int o = 0; o < N_POWER / 2; ++o) {
        apply_M();
        apply_M();
        v2f NS = vfma(PV[0], PV[0], vfma(PV[1], PV[1], PV[2] * PV[2]));
        float nsq = NS.x + NS.y;
        nsq = dpp_xor_add<0xB1>(nsq); nsq = dpp_xor_add<0x4E>(nsq);
        nsq = fmaf(pvC, pvC, fmaf(pvS, pvS, nsq));
        const float inv = __builtin_amdgcn_rsqf(nsq + 1e-24f);
        const v2f INV = {inv, inv};
#pragma unroll
        for (int k = 0; k < 3; ++k) PV[k] = PV[k] * INV;
        pvC *= inv;
        pvS *= inv;
    }
    float nsh, pA;   // -step/2, -step*PINV_S
    {
        v2f A0 = vfma(R0[0], PV[0], vfma(R0[1], PV[1], R0[2] * PV[2]));
        v2f A1 = vfma(R1[0], PV[0], vfma(R1[1], PV[1], R1[2] * PV[2]));
        v2f AA = vfma(RA[0], PV[0], vfma(RA[1], PV[1], RA[2] * PV[2]));
        float a0 = A0.x + A0.y, a1 = A1.x + A1.y, aA = AA.x + AA.y;
        a0 = dpp_xor_add<0xB1>(a0); a0 = dpp_xor_add<0x4E>(a0);
        a1 = dpp_xor_add<0xB1>(a1); a1 = dpp_xor_add<0x4E>(a1);
        aA = dpp_xor_add<0xB1>(aA);
        a0 = fmaf(c0, pvC, a0);
        a1 = fmaf(c1, pvC, a1);
        const float aC = fmaf(cB, pvC, -pvS);
        // pair sums of slack cols: after xor1, lanes {0,1} hold col2, {2,3} col3
        float tq = aA * aA;
        tq = dpp_xor_add<0x4E>(tq);     // col2^2 + col3^2 in every lane
        const float L = 0.5f * (a0 * a0 + a1 * a1) + PINV_S * (tq + aC * aC);
        const float step = __builtin_amdgcn_rcpf(L + 1e-6f);
        nsh = -0.5f * step;
        pA  = -PINV_S * step;
    }

    // ---- FISTA on the dual, z = y/step scale, packed, lambda ping-pong ----
    v2f LAE[3], LAO[3], ZV[3];
#pragma unroll
    for (int k = 0; k < 3; ++k) {
        LAE[k] = v2f{0.f, 0.f}; LAO[k] = v2f{0.f, 0.f}; ZV[k] = v2f{0.f, 0.f};
    }
    v2f laCSE = {0.f, 0.f}, laCSO = {0.f, 0.f}, zCS = {0.f, 0.f};  // {conn, slack2}

    auto half_step = [&](v2f (&ln_)[3], const v2f (&lp_)[3],
                         v2f& lnCS, v2f lpCS, v2f Bv) {
        v2f A0 = vfma(R0[0], ZV[0], vfma(R0[1], ZV[1], R0[2] * ZV[2]));
        v2f A1 = vfma(R1[0], ZV[0], vfma(R1[1], ZV[1], R1[2] * ZV[2]));
        v2f AA = vfma(RA[0], ZV[0], vfma(RA[1], ZV[1], RA[2] * ZV[2]));
        float a0 = A0.x + A0.y, a1 = A1.x + A1.y, aA = AA.x + AA.y;
        a0 = dpp_xor_add<0xB1>(a0); a0 = dpp_xor_add<0x4E>(a0);
        a1 = dpp_xor_add<0xB1>(a1); a1 = dpp_xor_add<0x4E>(a1);
        aA = dpp_xor_add<0xB1>(aA);
        const v2f tC = CB2 * zCS;           // {cB*zC, -zS}
        const float sCz = tC.x + tC.y;
        const float x0 = fmaf(nsh, fmaf(c0, zCS.x, a0), u0);  // x = -(q + A^T y)*Pinv
        const float x1 = fmaf(nsh, fmaf(c1, zCS.x, a1), u1);
        const float xA = pA * aA;
        const float xC = pA * sCz;
        const v2f X0 = {x0, x0}, X1 = {x1, x1}, XA = {xA, xA}, XC = {xC, xC};
#pragma unroll
        for (int k = 0; k < 3; ++k) {
            const v2f resid = vfma(R0[k], X0, vfma(R1[k], X1, vfma(RA[k], XA, NB[k])));
            const v2f l = vmax0(ZV[k] + resid);
            ZV[k] = vfma(Bv, l - lp_[k], l);
            ln_[k] = l;
        }
        {   // packed conn(.x) + slack2(.y)
            const v2f resid = vfma(C0v, X0, vfma(C1v, X1, vfma(CB2, XC, NCBv)));
            const v2f l = vmax0(zCS + resid);
            zCS = vfma(Bv, l - lpCS, l);
            lnCS = l;
        }
    };

#pragma unroll 1
    for (int o = 0; o < N_FISTA / 2; ++o) {
        const BQuadDup bq = BETAD.q[o];   // one s_load_dwordx4 per 2 iterations
        const v2f B0 = {bq.b[0], bq.b[1]};
        const v2f B1 = {bq.b[2], bq.b[3]};
        half_step(LAE, LAO, laCSE, laCSO, B0);  // it=2o   writes E
        half_step(LAO, LAE, laCSO, laCSE, B1);  // it=2o+1 writes O
    }

    // ---- Final primal from lambda = step*Lambda (last write was LAO / laCSO) ----
    v2f A0 = vfma(R0[0], LAO[0], vfma(R0[1], LAO[1], R0[2] * LAO[2]));
    v2f A1 = vfma(R1[0], LAO[0], vfma(R1[1], LAO[1], R1[2] * LAO[2]));
    float a0 = A0.x + A0.y, a1 = A1.x + A1.y;
    a0 = dpp_xor_add<0xB1>(a0); a0 = dpp_xor_add<0x4E>(a0);
    a1 = dpp_xor_add<0xB1>(a1); a1 = dpp_xor_add<0x4E>(a1);
    a0 = fmaf(c0, laCSO.x, a0);
    a1 = fmaf(c1, laCSO.x, a1);
    if (sub == 0) {
        out[2 * p]     = fmaf(nsh, a0, u0);
        out[2 * p + 1] = fmaf(nsh, a1, u1);
    }
}

extern "C" void kernel_launch(void* const* d_in, const int* in_sizes, int n_in,
                              void* d_out, int out_size, void* d_ws, size_t ws_size,
                              hipStream_t stream) {
    const float* u_nom    = (const float*)d_in[0];
    const float* v_cur    = (const float*)d_in[1];
    const float* p_obs    = (const float*)d_in[2];
    const float* obs_mask = (const float*)d_in[3];
    const float* p_ag     = (const float*)d_in[4];
    const float* v_ag     = (const float*)d_in[5];
    const float* ag_mask  = (const float*)d_in[6];
    const float* p_c      = (const float*)d_in[7];
    const float* v_c      = (const float*)d_in[8];
    const float* c_mask   = (const float*)d_in[9];
    float* out = (float*)d_out;

    const int B = in_sizes[0] / 2;
    const long long threads = 4LL * B;
    const int grid = (int)((threads + 255) / 256);
    cbf_fista9<<<grid, 256, 0, stream>>>(
        u_nom, v_cur, p_obs, obs_mask, p_ag, v_ag, ag_mask, p_c, v_c, c_mask, out, B);
}